// Round 12
// baseline (77.202 us; speedup 1.0000x reference)
//
#include <hip/hip_runtime.h>

#define B_ 4
#define T_ 8
#define N_ 256
#define F_ 16
#define D_ 64
#define NP (D_/2)       // 32 pairs per row
#define CHUNK 8
#define NCH (N_/CHUNK)  // 32 -> main grid = 1024 blocks

#define SC 2.8853900817779268f        // 2*log2(e): exp2(SC*x) = e^{2x}
#define LOG2E 1.4426950408889634f

typedef __attribute__((ext_vector_type(16))) float f32x16;

__device__ __forceinline__ float fast_exp2(float x) { return __builtin_amdgcn_exp2f(x); }
__device__ __forceinline__ float fast_rcp(float x)  { return __builtin_amdgcn_rcpf(x); }

// ---------------- prologue ----------------
// Eq[row][d] = exp2(SC*(q Wq + bq)_d)        (row-major)
// EkT[bt][d][m] = exp2(SC*(k Wk + bk)_d)     (transposed -> coalesced main loads)
__global__ __launch_bounds__(256)
void tattn_proj_kernel(const float* __restrict__ query,
                       const float* __restrict__ keys,
                       const float* __restrict__ Wq, const float* __restrict__ bq,
                       const float* __restrict__ Wk, const float* __restrict__ bk,
                       float* __restrict__ Eq, float* __restrict__ EkT)
{
    const int tid = threadIdx.x;
    const int row = blockIdx.x * 4 + (tid >> 6);   // 4 rows (waves) per block
    const int j   = tid & 63;
    const int NQ  = B_ * N_;

    if (row < NQ) {                                // wave-uniform branch
        const float* in = query + (size_t)row * F_;
        float acc = bq[j];
        #pragma unroll
        for (int f = 0; f < F_; ++f) acc = fmaf(in[f], Wq[f * D_ + j], acc);
        Eq[(size_t)row * D_ + j] = fast_exp2(acc * SC);
    } else {
        const int r  = row - NQ;                   // r = bt*N + n
        const int bt = r >> 8, n = r & (N_ - 1);
        const float* in = keys + (size_t)r * F_;
        float acc = bk[j];
        #pragma unroll
        for (int f = 0; f < F_; ++f) acc = fmaf(in[f], Wk[f * D_ + j], acc);
        EkT[((size_t)bt * D_ + j) * N_ + n] = fast_exp2(acc * SC);
    }
}

// ---------------- main ----------------
// score(n,m) = Wsum - sum_pairs (2w0(1+x1)+2w1(1+x0)) * rcp((1+x0)(1+x1)), x_d = eq_d*ek_d
// eq: 4x s_load_dwordx16 -> SGPRs (one drain/row). wt: LDS-resident (compiler demotes wv).
// VGPR=84 measured (R10) -> (256,5) keeps >=4 blocks/CU resident, zero tail, no spill.
__global__ __launch_bounds__(256, 5)
void tattn_main_kernel(const float* __restrict__ Eq,
                       const float* __restrict__ EkT,
                       const float* __restrict__ wt,
                       float* __restrict__ out)
{
    __shared__ float pbuf[CHUNK][N_];   // 8 KB
    __shared__ float wls[D_];
    __shared__ float totL[CHUNK];

    const int tid = threadIdx.x;
    const int bid = blockIdx.x;
    const int ch  = bid % NCH;
    const int t   = (bid / NCH) % T_;
    const int b   = bid / (NCH * T_);
    const int n0  = ch * CHUNK;
    const int bt  = b * T_ + t;

    if (tid < D_) wls[tid] = 2.0f * wt[tid];

    // Ek column for key m=tid: 64 coalesced wave loads
    float kreg[D_];
    {
        const float* kp = EkT + (size_t)bt * D_ * N_ + tid;
        #pragma unroll
        for (int d = 0; d < D_; ++d) kreg[d] = kp[(size_t)d * N_];
    }
    __syncthreads();

    float wv[D_];
    #pragma unroll
    for (int d = 0; d < D_; d += 4) {
        float4 v = *reinterpret_cast<const float4*>(&wls[d]);
        wv[d] = v.x; wv[d+1] = v.y; wv[d+2] = v.z; wv[d+3] = v.w;
    }
    float Wsum = 0.f;
    #pragma unroll
    for (int d = 0; d < D_; ++d) Wsum += wv[d];
    Wsum *= 0.5f;

    const int lane = tid & 63;
    const int wid  = tid >> 6;
    const size_t obase = ((size_t)(bt * N_ + n0)) * N_ + tid;

    const float* eqrow = Eq + ((size_t)(b * N_ + n0)) * D_;

    #pragma unroll 1
    for (int nn = 0; nn < CHUNK; ++nn) {
        f32x16 e0, e1, e2, e3;
        asm volatile("s_load_dwordx16 %0, %4, 0x0\n\t"
                     "s_load_dwordx16 %1, %4, 0x40\n\t"
                     "s_load_dwordx16 %2, %4, 0x80\n\t"
                     "s_load_dwordx16 %3, %4, 0xc0"
                     : "=&s"(e0), "=&s"(e1), "=&s"(e2), "=&s"(e3)
                     : "s"(eqrow));
        asm volatile("s_waitcnt lgkmcnt(0)"
                     : "+s"(e0), "+s"(e1), "+s"(e2), "+s"(e3));
        __builtin_amdgcn_sched_barrier(0);

        float a0 = 0.f, a1 = 0.f, a2 = 0.f, a3 = 0.f;
        #pragma unroll
        for (int pr = 0; pr < NP; ++pr) {
            float eqa, eqb;
            if      (pr <  8) { eqa = e0[2*pr];      eqb = e0[2*pr+1];  }
            else if (pr < 16) { eqa = e1[2*pr-16];   eqb = e1[2*pr-15]; }
            else if (pr < 24) { eqa = e2[2*pr-32];   eqb = e2[2*pr-31]; }
            else              { eqa = e3[2*pr-48];   eqb = e3[2*pr-47]; }
            float pA = fmaf(eqa, kreg[2*pr+0], 1.0f);
            float qA = fmaf(eqb, kreg[2*pr+1], 1.0f);
            float nA = fmaf(wv[2*pr+1], pA, wv[2*pr] * qA);
            float r  = fast_rcp(pA * qA);
            if      ((pr & 3) == 0) a0 = fmaf(nA, r, a0);
            else if ((pr & 3) == 1) a1 = fmaf(nA, r, a1);
            else if ((pr & 3) == 2) a2 = fmaf(nA, r, a2);
            else                    a3 = fmaf(nA, r, a3);
        }
        float score = Wsum - ((a0 + a1) + (a2 + a3));
        pbuf[nn][tid] = fast_exp2(score * LOG2E);
        eqrow += D_;
    }
    __syncthreads();

    #pragma unroll
    for (int rr = 0; rr < 2; ++rr) {
        const int row = wid * 2 + rr;
        float4 v = *reinterpret_cast<const float4*>(&pbuf[row][lane * 4]);
        float s = (v.x + v.y) + (v.z + v.w);
        #pragma unroll
        for (int off = 32; off >= 1; off >>= 1) s += __shfl_xor(s, off);
        if (lane == 0) totL[row] = s;
    }
    __syncthreads();

    #pragma unroll
    for (int nn = 0; nn < CHUNK; ++nn)
        out[obase + (size_t)nn * N_] = pbuf[nn][tid] * fast_rcp(totL[nn]);
}

extern "C" void kernel_launch(void* const* d_in, const int* in_sizes, int n_in,
                              void* d_out, int out_size, void* d_ws, size_t ws_size,
                              hipStream_t stream) {
    const float* query = (const float*)d_in[0];
    const float* keys  = (const float*)d_in[1];
    const float* Wq    = (const float*)d_in[2];
    const float* bq    = (const float*)d_in[3];
    const float* Wk    = (const float*)d_in[4];
    const float* bk    = (const float*)d_in[5];
    const float* wt    = (const float*)d_in[6];
    float* out = (float*)d_out;

    float* Eq  = (float*)d_ws;                         // B*N*D   floats (256 KB)
    float* EkT = Eq + (size_t)B_ * N_ * D_;            // B*T*D*N floats (2 MB)

    const int rows = B_ * N_ + B_ * T_ * N_;           // 9216, 4 rows/block
    hipLaunchKernelGGL(tattn_proj_kernel, dim3(rows / 4), dim3(256), 0, stream,
                       query, keys, Wq, bq, Wk, bk, Eq, EkT);

    hipLaunchKernelGGL(tattn_main_kernel, dim3(B_ * T_ * NCH), dim3(256), 0, stream,
                       Eq, EkT, wt, out);
}

// Round 13
// 31.871 us; speedup vs baseline: 2.4224x; 2.4224x over previous
//
#include <hip/hip_runtime.h>

#define B_ 4
#define T_ 8
#define N_ 256
#define F_ 16
#define D_ 64
#define NP (D_/2)       // 32 pairs per row
#define CHUNK 8
#define NCH (N_/CHUNK)  // 32 -> grid = 1024 blocks = 4/CU

#define SC 2.8853900817779268f        // 2*log2(e): exp2(SC*x) = e^{2x}
#define LOG2E 1.4426950408889634f

typedef __attribute__((ext_vector_type(16))) float f32x16;

__device__ __forceinline__ float fast_exp2(float x) { return __builtin_amdgcn_exp2f(x); }
__device__ __forceinline__ float fast_rcp(float x)  { return __builtin_amdgcn_rcpf(x); }
__device__ __forceinline__ float rl(float v, int l) {   // lane-broadcast -> uniform (SGPR)
    return __uint_as_float(__builtin_amdgcn_readlane(__float_as_uint(v), l));
}

// ---------------- fully fused: proj + scores + softmax ----------------
__global__ __launch_bounds__(256, 4)
void tattn_fused_kernel(const float* __restrict__ query,
                        const float* __restrict__ keys,
                        const float* __restrict__ Wq, const float* __restrict__ bq,
                        const float* __restrict__ Wk, const float* __restrict__ bk,
                        const float* __restrict__ wt,
                        float* __restrict__ out)
{
    __shared__ float qe[CHUNK][D_];     // 2 KB: eq rows for this block
    __shared__ float pbuf[CHUNK][N_];   // 8 KB
    __shared__ float totL[CHUNK];

    const int tid = threadIdx.x;
    const int bid = blockIdx.x;
    const int ch  = bid % NCH;
    const int t   = (bid / NCH) % T_;
    const int b   = bid / (NCH * T_);
    const int n0  = ch * CHUNK;
    const int bt  = b * T_ + t;
    const int lane = tid & 63;
    const int wid  = tid >> 6;

    // ---- wt -> 64 SGPRs (input buffer: scalar-cache coherent) ----
    f32x16 w0, w1, w2, w3;
    asm volatile("s_load_dwordx16 %0, %4, 0x0\n\t"
                 "s_load_dwordx16 %1, %4, 0x40\n\t"
                 "s_load_dwordx16 %2, %4, 0x80\n\t"
                 "s_load_dwordx16 %3, %4, 0xc0"
                 : "=&s"(w0), "=&s"(w1), "=&s"(w2), "=&s"(w3)
                 : "s"(wt));

    // ---- k-projection for key m=tid, entirely in registers ----
    float kr[D_];
    {
        const float* kp = keys + ((size_t)bt * N_ + tid) * F_;
        float4 kf0 = *reinterpret_cast<const float4*>(kp + 0);
        float4 kf1 = *reinterpret_cast<const float4*>(kp + 4);
        float4 kf2 = *reinterpret_cast<const float4*>(kp + 8);
        float4 kf3 = *reinterpret_cast<const float4*>(kp + 12);
        float kf[F_] = {kf0.x,kf0.y,kf0.z,kf0.w, kf1.x,kf1.y,kf1.z,kf1.w,
                        kf2.x,kf2.y,kf2.z,kf2.w, kf3.x,kf3.y,kf3.z,kf3.w};
        #pragma unroll
        for (int d4 = 0; d4 < 16; ++d4) {
            float4 bv = reinterpret_cast<const float4*>(bk)[d4];   // uniform -> L1 broadcast
            kr[4*d4+0] = bv.x; kr[4*d4+1] = bv.y; kr[4*d4+2] = bv.z; kr[4*d4+3] = bv.w;
        }
        #pragma unroll
        for (int f = 0; f < F_; ++f) {
            const float kfv = kf[f];
            const float4* wrow = reinterpret_cast<const float4*>(Wk + f * D_);
            #pragma unroll
            for (int d4 = 0; d4 < 16; ++d4) {
                float4 wv4 = wrow[d4];                             // uniform -> L1 broadcast
                kr[4*d4+0] = fmaf(kfv, wv4.x, kr[4*d4+0]);
                kr[4*d4+1] = fmaf(kfv, wv4.y, kr[4*d4+1]);
                kr[4*d4+2] = fmaf(kfv, wv4.z, kr[4*d4+2]);
                kr[4*d4+3] = fmaf(kfv, wv4.w, kr[4*d4+3]);
            }
        }
        #pragma unroll
        for (int d = 0; d < D_; ++d) kr[d] = fast_exp2(kr[d] * SC);
    }

    // ---- q-projection: 8 rows x 64 d, 2 outputs/thread -> LDS ----
    #pragma unroll
    for (int i = 0; i < 2; ++i) {
        const int e = tid + i * 256;
        const int r = e >> 6, d = e & 63;
        const float* qp = query + ((size_t)b * N_ + n0 + r) * F_;  // row uniform per 64-group
        float a = bq[d];                                           // coalesced
        #pragma unroll
        for (int f = 0; f < F_; ++f) a = fmaf(qp[f], Wq[f * D_ + d], a);  // Wq coalesced
        qe[r][d] = fast_exp2(a * SC);
    }

    // Wsum via wave reduce of wt (coalesced per-lane load)
    float Ws = wt[lane];
    #pragma unroll
    for (int off = 32; off >= 1; off >>= 1) Ws += __shfl_xor(Ws, off);
    const float WsL  = Ws * LOG2E;
    const float n2L  = -2.0f * LOG2E;

    asm volatile("s_waitcnt lgkmcnt(0)" : "+s"(w0), "+s"(w1), "+s"(w2), "+s"(w3));
    __syncthreads();

#define WV(IDX) ((IDX) < 16 ? w0[(IDX)] : (IDX) < 32 ? w1[(IDX)-16] \
                : (IDX) < 48 ? w2[(IDX)-32] : w3[(IDX)-48])

    // ---- hot loop: 8 rows; eq via 1 ds_read + readlane; wt from SGPR ----
    #pragma unroll 1
    for (int nn = 0; nn < CHUNK; ++nn) {
        const float eqvn = qe[nn][lane];    // lane l holds eq[nn][l]
        float a0 = 0.f, a1 = 0.f, a2 = 0.f, a3 = 0.f;
        #pragma unroll
        for (int pr = 0; pr < NP; ++pr) {
            const float eqa = rl(eqvn, 2*pr);
            const float eqb = rl(eqvn, 2*pr+1);
            const float w0s = WV(2*pr);
            const float w1s = WV(2*pr+1);
            float pA = fmaf(eqa, kr[2*pr+0], 1.0f);   // 1 SGPR operand
            float qA = fmaf(eqb, kr[2*pr+1], 1.0f);
            float nA = fmaf(w1s, pA, w0s * qA);       // 1 SGPR per op
            float r  = fast_rcp(pA * qA);
            if      ((pr & 3) == 0) a0 = fmaf(nA, r, a0);
            else if ((pr & 3) == 1) a1 = fmaf(nA, r, a1);
            else if ((pr & 3) == 2) a2 = fmaf(nA, r, a2);
            else                    a3 = fmaf(nA, r, a3);
        }
        const float S = (a0 + a1) + (a2 + a3);
        pbuf[nn][tid] = fast_exp2(fmaf(n2L, S, WsL));  // p = exp2(L2E*(Wsum-2S))
    }
#undef WV
    __syncthreads();

    // ---- per-row totals: wave w reduces rows 2w, 2w+1 ----
    #pragma unroll
    for (int rr = 0; rr < 2; ++rr) {
        const int row = wid * 2 + rr;
        float4 v = *reinterpret_cast<const float4*>(&pbuf[row][lane * 4]);
        float s = (v.x + v.y) + (v.z + v.w);
        #pragma unroll
        for (int off = 32; off >= 1; off >>= 1) s += __shfl_xor(s, off);
        if (lane == 0) totL[row] = s;
    }
    __syncthreads();

    const size_t obase = ((size_t)(bt * N_ + n0)) * N_ + tid;
    #pragma unroll
    for (int nn = 0; nn < CHUNK; ++nn)
        out[obase + (size_t)nn * N_] = pbuf[nn][tid] * fast_rcp(totL[nn]);
}

extern "C" void kernel_launch(void* const* d_in, const int* in_sizes, int n_in,
                              void* d_out, int out_size, void* d_ws, size_t ws_size,
                              hipStream_t stream) {
    const float* query = (const float*)d_in[0];
    const float* keys  = (const float*)d_in[1];
    const float* Wq    = (const float*)d_in[2];
    const float* bq    = (const float*)d_in[3];
    const float* Wk    = (const float*)d_in[4];
    const float* bk    = (const float*)d_in[5];
    const float* wt    = (const float*)d_in[6];
    float* out = (float*)d_out;

    hipLaunchKernelGGL(tattn_fused_kernel, dim3(B_ * T_ * NCH), dim3(256), 0, stream,
                       query, keys, Wq, bq, Wk, bk, wt, out);
}